// Round 7
// baseline (275.343 us; speedup 1.0000x reference)
//
#include <hip/hip_runtime.h>
#include <hip/hip_bf16.h>
#include <stdint.h>
#include <math.h>

typedef __bf16 bf16_t;
typedef __bf16 bf16x8 __attribute__((ext_vector_type(8)));
typedef float  f32x4  __attribute__((ext_vector_type(4)));
typedef float  f32x16 __attribute__((ext_vector_type(16)));
typedef unsigned int u32;

#define S_SZ 4096
#define HS   64
#define OUT_B_STRIDE (256 * 64 * 64)
#define LOG2E 1.4426950408889634f

static __device__ __forceinline__ u32 pack2(__bf16 a, __bf16 b) {
    return (u32)__builtin_bit_cast(uint16_t, a) | ((u32)__builtin_bit_cast(uint16_t, b) << 16);
}

// =======================================================================================
// prep: blocks 0..47: W -> bf16 hi/lo (Q rows pre-scaled by log2e), coalesced.
//       blocks 48..111: R[n][t][d] = rel_h + rel_w (bf16), t = h2*256 + o, LDS-staged.
// =======================================================================================
__global__ __launch_bounds__(256)
void prep_kernel(const float* __restrict__ wq, const float* __restrict__ wk,
                 const float* __restrict__ wv, const float* __restrict__ rel_h,
                 const float* __restrict__ rel_w,
                 bf16_t* __restrict__ Wh, bf16_t* __restrict__ Wl,
                 bf16_t* __restrict__ Rt)
{
    const int blk = blockIdx.x;
    if (blk < 48) {
        const int base = blk * 4096;
        #pragma unroll
        for (int i = 0; i < 16; ++i) {
            const int e = base + i * 256 + threadIdx.x;
            const int o = e >> 8, c = e & 255;
            const float* src = o < 256 ? wq : (o < 512 ? wk : wv);
            float v = src[(size_t)(o & 255) * 256 + c];
            if (o < 256) v *= LOG2E;
            __bf16 h = (__bf16)v;
            Wh[e] = h;
            Wl[e] = (__bf16)(v - (float)h);
        }
    } else {
        const int rb = blk - 48;
        const int n = rb >> 4, h2 = rb & 15;
        __shared__ float rh[4096], rw[4096];
        for (int i = threadIdx.x; i < 4096; i += 256) {
            rh[i] = rel_h[n * 4096 + i];
            rw[i] = rel_w[n * 4096 + i];
        }
        __syncthreads();
        bf16_t* Rp = Rt + ((size_t)n * 4096 + h2 * 256) * 64;
        const int d0 = (threadIdx.x & 7) * 8;
        const int ob = threadIdx.x >> 3;
        #pragma unroll
        for (int i = 0; i < 8; ++i) {
            const int o  = i * 32 + ob;
            const int ih = (o & 3) * 16 + h2;
            const int iw = o >> 2;
            bf16x8 rv;
            #pragma unroll
            for (int dd = 0; dd < 8; ++dd)
                rv[dd] = (bf16_t)(rh[(d0 + dd) * 64 + ih] + rw[(d0 + dd) * 64 + iw]);
            *(bf16x8*)(Rp + (size_t)o * 64 + d0) = rv;
        }
    }
}

// =======================================================================================
// proj (R5 version, 64KB LDS, 2 blocks/CU): bf16 MFMA, 3-product hi/lo split,
// two-pass LDS-reassembled coalesced epilogue. grid 256, block 512 (8 waves).
// =======================================================================================
__global__ __launch_bounds__(512, 2)
void proj_kernel(const float* __restrict__ x,
                 const bf16_t* __restrict__ Wh, const bf16_t* __restrict__ Wl,
                 const float* __restrict__ bq, const float* __restrict__ bk,
                 const float* __restrict__ bv, const bf16_t* __restrict__ Rt,
                 bf16_t* __restrict__ q_ws, bf16_t* __restrict__ k2_ws,
                 bf16_t* __restrict__ vt2_ws)
{
    const int bx = blockIdx.x;
    const int b  = bx >> 6;
    const int h  = bx & 63;
    const int p0 = h * 64;
    const int n  = h & 3;
    const int h2 = h >> 2;
    const int bn = b * 4 + n;
    const int tid = threadIdx.x;

    __shared__ __align__(16) char SM[65536];   // XT hi/lo -> reused for epilogue

    {
        const int cpair = tid & 127, pg = tid >> 7;
        const int c0 = cpair * 2;
        const float* x0 = x + ((size_t)b * 256 + c0) * 4096 + p0 + pg * 16;
        const int sub = (c0 >> 6) * 128;
        const int u   = (c0 >> 3) & 7;
        const int e2  = (c0 & 7) * 2;
        #pragma unroll
        for (int i4 = 0; i4 < 4; ++i4) {
            f32x4 ra = *(const f32x4*)(x0 + i4 * 4);
            f32x4 rb = *(const f32x4*)(x0 + 4096 + i4 * 4);
            #pragma unroll
            for (int i = 0; i < 4; ++i) {
                const int p = pg * 16 + i4 * 4 + i;
                __bf16 ha = (__bf16)ra[i], hb = (__bf16)rb[i];
                float  la = ra[i] - (float)ha, lb = rb[i] - (float)hb;
                const int off = p * 512 + sub + ((u ^ (p & 7)) * 16) + e2;
                *(u32*)(SM + off)         = pack2(ha, hb);
                *(u32*)(SM + 32768 + off) = pack2((__bf16)la, (__bf16)lb);
            }
        }
    }
    __syncthreads();

    const int wid = tid >> 6, lane = tid & 63, l31 = lane & 31, hi = lane >> 5;

    int obs[3], pjs[3];
    const bf16_t* whp[3];
    const bf16_t* wlp[3];
    #pragma unroll
    for (int j = 0; j < 3; ++j) {
        const int of = (wid * 3 + j) * 32;
        pjs[j] = of >> 8;
        obs[j] = of & 255;
        whp[j] = Wh + (size_t)(of + l31) * 256 + hi * 8;
        wlp[j] = Wl + (size_t)(of + l31) * 256 + hi * 8;
    }

    const char* XHp = SM + l31 * 512;
    const char* XLp = SM + 32768 + l31 * 512;

    f32x16 acc[3][2] = {};

    #pragma unroll
    for (int ks = 0; ks < 16; ++ks) {
        bf16x8 wh[3], wl[3];
        #pragma unroll
        for (int j = 0; j < 3; ++j) {
            wh[j] = *(const bf16x8*)(whp[j] + ks * 16);
            wl[j] = *(const bf16x8*)(wlp[j] + ks * 16);
        }
        const int rb_ = (ks >> 2) * 128 + ((((ks * 2 + hi) & 7) ^ (l31 & 7)) * 16);
        bf16x8 xh[2], xl[2];
        #pragma unroll
        for (int pt = 0; pt < 2; ++pt) {
            xh[pt] = *(const bf16x8*)(XHp + pt * 16384 + rb_);
            xl[pt] = *(const bf16x8*)(XLp + pt * 16384 + rb_);
        }
        #pragma unroll
        for (int j = 0; j < 3; ++j)
            #pragma unroll
            for (int pt = 0; pt < 2; ++pt) {
                acc[j][pt] = __builtin_amdgcn_mfma_f32_32x32x16_bf16(wh[j], xh[pt], acc[j][pt], 0, 0, 0);
                acc[j][pt] = __builtin_amdgcn_mfma_f32_32x32x16_bf16(wh[j], xl[pt], acc[j][pt], 0, 0, 0);
                acc[j][pt] = __builtin_amdgcn_mfma_f32_32x32x16_bf16(wl[j], xh[pt], acc[j][pt], 0, 0, 0);
            }
    }
    __syncthreads();

    f32x4 bias[3][2][4];
    #pragma unroll
    for (int j = 0; j < 3; ++j) {
        const float* bp = pjs[j] == 0 ? bq : (pjs[j] == 1 ? bk : bv);
        #pragma unroll
        for (int g2 = 0; g2 < 4; ++g2) {
            f32x4 v = *(const f32x4*)(bp + obs[j] + hi * 4 + g2 * 8);
            if (pjs[j] == 0) {
                #pragma unroll
                for (int i = 0; i < 4; ++i) v[i] *= LOG2E;
            }
            bias[j][0][g2] = v;  bias[j][1][g2] = v;
        }
    }

    // pass 1: Q -> [0,32K), V -> [32,64K)
    #pragma unroll
    for (int j = 0; j < 3; ++j) {
        if (pjs[j] == 1) continue;
        #pragma unroll
        for (int pt = 0; pt < 2; ++pt) {
            const int d = pt * 32 + l31;
            #pragma unroll
            for (int g2 = 0; g2 < 4; ++g2)
                #pragma unroll
                for (int rr = 0; rr < 4; ++rr) {
                    const int o = obs[j] + rr + 4 * hi + 8 * g2;
                    const float v = acc[j][pt][g2 * 4 + rr] + bias[j][pt][g2][rr];
                    if (pjs[j] == 0) {
                        *(bf16_t*)(SM + o * 128 + d * 2) = (bf16_t)v;
                    } else {
                        *(bf16_t*)(SM + 32768 + d * 512 + ((o * 2) ^ ((d & 7) << 4))) = (bf16_t)v;
                    }
                }
        }
    }
    __syncthreads();
    {
        bf16_t* qp = q_ws + (size_t)bn * 4096 * 64;
        #pragma unroll
        for (int i = 0; i < 4; ++i) {
            const int c = i * 512 + tid;
            const int o = c >> 3, d8 = c & 7;
            uint4 v = *(const uint4*)(SM + c * 16);
            *(uint4*)(qp + (size_t)(o * 16 + h2) * 64 + d8 * 8) = v;
        }
        bf16_t* vp = vt2_ws + (size_t)bn * 64 * 4096 + h2 * 256;
        #pragma unroll
        for (int i = 0; i < 4; ++i) {
            const int c = i * 512 + tid;
            const int d = c >> 5, k = c & 31;
            uint4 v = *(const uint4*)(SM + 32768 + d * 512 + ((k * 16) ^ ((d & 7) << 4)));
            *(uint4*)(vp + (size_t)d * 4096 + k * 8) = v;
        }
    }
    __syncthreads();

    // pass 2: K -> [0,32K)
    #pragma unroll
    for (int j = 0; j < 3; ++j) {
        if (pjs[j] != 1) continue;
        #pragma unroll
        for (int pt = 0; pt < 2; ++pt) {
            const int d = pt * 32 + l31;
            #pragma unroll
            for (int g2 = 0; g2 < 4; ++g2)
                #pragma unroll
                for (int rr = 0; rr < 4; ++rr) {
                    const int o = obs[j] + rr + 4 * hi + 8 * g2;
                    *(bf16_t*)(SM + o * 128 + d * 2) =
                        (bf16_t)(acc[j][pt][g2 * 4 + rr] + bias[j][pt][g2][rr]);
                }
        }
    }
    __syncthreads();
    {
        const bf16_t* Rp = Rt + ((size_t)n * 4096 + h2 * 256) * 64;
        bf16_t* kp = k2_ws + ((size_t)bn * 4096 + h2 * 256) * 64;
        #pragma unroll
        for (int i = 0; i < 4; ++i) {
            const int c = i * 512 + tid;
            bf16x8 kv = *(const bf16x8*)(SM + c * 16);
            bf16x8 rv = *(const bf16x8*)(Rp + c * 8);
            bf16x8 res;
            #pragma unroll
            for (int ii = 0; ii < 8; ++ii)
                res[ii] = (__bf16)((float)kv[ii] + (float)rv[ii]);
            *(bf16x8*)(kp + c * 8) = res;
        }
    }
}

// =======================================================================================
// flash attention, ALL-REGISTER K/V (no LDS, no barriers): K/V are L2/L1-resident
// (1MB per bn, 2 bn per XCD; all 4 waves read identical tile addresses -> L1 hits).
// Software-pipelined one tile deep. grid 512 (16 bn x 32 qb), block 256 = 4 waves.
// =======================================================================================
__global__ __launch_bounds__(256, 2)
void attn_kernel(const bf16_t* __restrict__ q_ws, const bf16_t* __restrict__ k_ws,
                 const bf16_t* __restrict__ vt_ws, float* __restrict__ out)
{
    const int tid  = threadIdx.x;
    const int wid  = tid >> 6;
    const int lane = tid & 63;
    const int l31  = lane & 31;
    const int hi   = lane >> 5;

    // bijective XCD swizzle: each XCD gets 64 consecutive swz = 2 bn
    const int wg  = blockIdx.x;
    const int swz = (wg & 7) * 64 + (wg >> 3);
    const int bn  = swz >> 5;
    const int qb  = swz & 31;
    const int b   = bn >> 2, n = bn & 3;

    const bf16_t* Qb = q_ws + (size_t)bn * S_SZ * HS;
    // per-lane fragment base pointers (logical slot (2dk+hi) -> elem off dk*16 + hi*8)
    const bf16_t* Kp = k_ws  + (size_t)bn * S_SZ * HS + l31 * HS + hi * 8;
    const bf16_t* Vp = vt_ws + (size_t)bn * HS * S_SZ + (size_t)l31 * S_SZ + hi * 8;

    const int q = qb * 128 + wid * 32 + l31;
    bf16x8 qf[4];
    #pragma unroll
    for (int dk = 0; dk < 4; ++dk)
        qf[dk] = *(const bf16x8*)(Qb + (size_t)q * HS + dk * 16 + hi * 8);

    f32x16 oacc[2];
    f32x16 Z16;
    #pragma unroll
    for (int i = 0; i < 16; ++i) { oacc[0][i] = 0.f; oacc[1][i] = 0.f; Z16[i] = 0.f; }
    float lsum = 0.f;

#define LOADK(KF, T)                                                                   \
    { const bf16_t* p_ = Kp + (size_t)(T) * (64 * HS);                                 \
      _Pragma("unroll")                                                                \
      for (int hh = 0; hh < 2; ++hh)                                                   \
      _Pragma("unroll")                                                                \
      for (int dk = 0; dk < 4; ++dk)                                                   \
          KF[hh][dk] = *(const bf16x8*)(p_ + hh * (32 * HS) + dk * 16); }

#define LOADV(VF, T)                                                                   \
    { const bf16_t* p_ = Vp + (T) * 64;                                                \
      _Pragma("unroll")                                                                \
      for (int dh = 0; dh < 2; ++dh)                                                   \
      _Pragma("unroll")                                                                \
      for (int kk = 0; kk < 4; ++kk)                                                   \
          VF[dh][kk] = *(const bf16x8*)(p_ + (size_t)dh * (32 * S_SZ) + kk * 16); }

#define TILE(KF, VF)                                                                   \
    { f32x16 sacc[2];                                                                  \
      __builtin_amdgcn_s_setprio(1);                                                   \
      _Pragma("unroll")                                                                \
      for (int hh = 0; hh < 2; ++hh) {                                                 \
          sacc[hh] = __builtin_amdgcn_mfma_f32_32x32x16_bf16(KF[hh][0], qf[0], Z16, 0, 0, 0); \
          _Pragma("unroll")                                                            \
          for (int dk = 1; dk < 4; ++dk)                                               \
              sacc[hh] = __builtin_amdgcn_mfma_f32_32x32x16_bf16(KF[hh][dk], qf[dk], sacc[hh], 0, 0, 0); \
      }                                                                                \
      __builtin_amdgcn_s_setprio(0);                                                   \
      u32 Wd[2][4][2];                                                                 \
      float ps[4] = {0.f, 0.f, 0.f, 0.f};                                              \
      _Pragma("unroll")                                                                \
      for (int hh = 0; hh < 2; ++hh)                                                   \
      _Pragma("unroll")                                                                \
      for (int c = 0; c < 4; ++c)                                                      \
      _Pragma("unroll")                                                                \
      for (int tt = 0; tt < 2; ++tt) {                                                 \
          float pa = __builtin_amdgcn_exp2f(sacc[hh][c * 4 + tt * 2]);                 \
          float pb = __builtin_amdgcn_exp2f(sacc[hh][c * 4 + tt * 2 + 1]);             \
          ps[c] += pa + pb;                                                            \
          u32 w_;                                                                      \
          asm("v_cvt_pk_bf16_f32 %0, %1, %2" : "=v"(w_) : "v"(pa), "v"(pb));           \
          Wd[hh][c][tt] = w_; }                                                        \
      lsum += (ps[0] + ps[1]) + (ps[2] + ps[3]);                                       \
      u32 F[4][4];                                                                     \
      _Pragma("unroll")                                                                \
      for (int hh = 0; hh < 2; ++hh)                                                   \
      _Pragma("unroll")                                                                \
      for (int pr = 0; pr < 2; ++pr)                                                   \
      _Pragma("unroll")                                                                \
      for (int tt = 0; tt < 2; ++tt) {                                                 \
          u32 a_ = Wd[hh][2 * pr][tt], b_ = Wd[hh][2 * pr + 1][tt];                    \
          asm("v_permlane32_swap_b32 %0, %1" : "+v"(a_), "+v"(b_));                    \
          F[2 * hh + pr][tt]     = a_;                                                 \
          F[2 * hh + pr][2 + tt] = b_; }                                               \
      __builtin_amdgcn_s_setprio(1);                                                   \
      _Pragma("unroll")                                                                \
      for (int dh = 0; dh < 2; ++dh)                                                   \
      _Pragma("unroll")                                                                \
      for (int kk = 0; kk < 4; ++kk) {                                                 \
          union { u32 u[4]; bf16x8 v; } pf;                                            \
          pf.u[0] = F[kk][0]; pf.u[1] = F[kk][1]; pf.u[2] = F[kk][2]; pf.u[3] = F[kk][3]; \
          oacc[dh] = __builtin_amdgcn_mfma_f32_32x32x16_bf16(VF[dh][kk], pf.v, oacc[dh], 0, 0, 0); } \
      __builtin_amdgcn_s_setprio(0); }

    bf16x8 kfA[2][4], kfB[2][4], vf[2][4];

    LOADK(kfA, 0);
    for (int t = 0; t < 64; t += 2) {
        LOADV(vf, t);
        LOADK(kfB, t + 1);
        TILE(kfA, vf);
        LOADV(vf, t + 1);
        { const int t2 = (t + 2 < 64) ? t + 2 : 63; LOADK(kfA, t2); }
        TILE(kfB, vf);
    }
#undef TILE
#undef LOADV
#undef LOADK

    // ---- epilogue ----
    float lt  = lsum + __shfl_xor(lsum, 32);
    float inv = 1.0f / lt;
    float* outp = out + (size_t)b * OUT_B_STRIDE + (size_t)q * 256 + n * 64;
    #pragma unroll
    for (int dh = 0; dh < 2; ++dh)
        #pragma unroll
        for (int g2 = 0; g2 < 4; ++g2) {
            f32x4 v4;
            #pragma unroll
            for (int r = 0; r < 4; ++r) v4[r] = oacc[dh][g2 * 4 + r] * inv;
            *(f32x4*)(outp + dh * 32 + g2 * 8 + hi * 4) = v4;
        }
}

extern "C" void kernel_launch(void* const* d_in, const int* in_sizes, int n_in,
                              void* d_out, int out_size, void* d_ws, size_t ws_size,
                              hipStream_t stream)
{
    const float* x     = (const float*)d_in[0];
    const float* wq    = (const float*)d_in[1];
    const float* bq    = (const float*)d_in[2];
    const float* wk    = (const float*)d_in[3];
    const float* bk    = (const float*)d_in[4];
    const float* wv    = (const float*)d_in[5];
    const float* bv    = (const float*)d_in[6];
    const float* rel_h = (const float*)d_in[7];
    const float* rel_w = (const float*)d_in[8];
    float* out = (float*)d_out;

    bf16_t* q_ws   = (bf16_t*)d_ws;
    bf16_t* k2_ws  = q_ws  + (size_t)16 * S_SZ * HS;
    bf16_t* vt2_ws = k2_ws + (size_t)16 * S_SZ * HS;

    // scratch in d_out's tail (attn fully overwrites out afterwards)
    bf16_t* end = (bf16_t*)d_out + (size_t)out_size * 2;
    bf16_t* Wl  = end - 196608;
    bf16_t* Wh  = Wl - 196608;
    bf16_t* Rt  = Wh - 1048576;

    prep_kernel<<<112, 256, 0, stream>>>(wq, wk, wv, rel_h, rel_w, Wh, Wl, Rt);
    proj_kernel<<<256, 512, 0, stream>>>(x, Wh, Wl, bq, bk, bv, Rt,
                                         q_ws, k2_ws, vt2_ws);
    attn_kernel<<<512, 256, 0, stream>>>(q_ws, k2_ws, vt2_ws, out);
}

// Round 8
// 137.791 us; speedup vs baseline: 1.9983x; 1.9983x over previous
//
#include <hip/hip_runtime.h>
#include <hip/hip_bf16.h>
#include <stdint.h>
#include <math.h>

typedef __bf16 bf16_t;
typedef __bf16 bf16x8 __attribute__((ext_vector_type(8)));
typedef float  f32x4  __attribute__((ext_vector_type(4)));
typedef float  f32x16 __attribute__((ext_vector_type(16)));
typedef unsigned int u32;

#define S_SZ 4096
#define HS   64
#define OUT_B_STRIDE (256 * 64 * 64)
#define LOG2E 1.4426950408889634f

// async global->LDS, 16B per lane, dest = wave-uniform base + lane*16
#define GLOAD_LDS(gsrc, ldst)                                                              \
    __builtin_amdgcn_global_load_lds((__attribute__((address_space(1))) void*)(void*)(gsrc), \
                                     (__attribute__((address_space(3))) void*)(void*)(ldst),  \
                                     16, 0, 0)

static __device__ __forceinline__ u32 pack2(__bf16 a, __bf16 b) {
    return (u32)__builtin_bit_cast(uint16_t, a) | ((u32)__builtin_bit_cast(uint16_t, b) << 16);
}

// =======================================================================================
// prep: blocks 0..47: W -> bf16 hi/lo (Q rows pre-scaled by log2e), coalesced.
//       blocks 48..111: R[n][t][d] = rel_h + rel_w (bf16), t = h2*256 + o, LDS-staged.
// =======================================================================================
__global__ __launch_bounds__(256)
void prep_kernel(const float* __restrict__ wq, const float* __restrict__ wk,
                 const float* __restrict__ wv, const float* __restrict__ rel_h,
                 const float* __restrict__ rel_w,
                 bf16_t* __restrict__ Wh, bf16_t* __restrict__ Wl,
                 bf16_t* __restrict__ Rt)
{
    const int blk = blockIdx.x;
    if (blk < 48) {
        const int base = blk * 4096;
        #pragma unroll
        for (int i = 0; i < 16; ++i) {
            const int e = base + i * 256 + threadIdx.x;
            const int o = e >> 8, c = e & 255;
            const float* src = o < 256 ? wq : (o < 512 ? wk : wv);
            float v = src[(size_t)(o & 255) * 256 + c];
            if (o < 256) v *= LOG2E;
            __bf16 h = (__bf16)v;
            Wh[e] = h;
            Wl[e] = (__bf16)(v - (float)h);
        }
    } else {
        const int rb = blk - 48;
        const int n = rb >> 4, h2 = rb & 15;
        __shared__ float rh[4096], rw[4096];
        for (int i = threadIdx.x; i < 4096; i += 256) {
            rh[i] = rel_h[n * 4096 + i];
            rw[i] = rel_w[n * 4096 + i];
        }
        __syncthreads();
        bf16_t* Rp = Rt + ((size_t)n * 4096 + h2 * 256) * 64;
        const int d0 = (threadIdx.x & 7) * 8;
        const int ob = threadIdx.x >> 3;
        #pragma unroll
        for (int i = 0; i < 8; ++i) {
            const int o  = i * 32 + ob;
            const int ih = (o & 3) * 16 + h2;
            const int iw = o >> 2;
            bf16x8 rv;
            #pragma unroll
            for (int dd = 0; dd < 8; ++dd)
                rv[dd] = (bf16_t)(rh[(d0 + dd) * 64 + ih] + rw[(d0 + dd) * 64 + iw]);
            *(bf16x8*)(Rp + (size_t)o * 64 + d0) = rv;
        }
    }
}

// =======================================================================================
// proj (64KB LDS, 2 blocks/CU): bf16 MFMA, 3-product hi/lo split, two-pass
// LDS-reassembled coalesced epilogue. grid 256, block 512 (8 waves).
// =======================================================================================
__global__ __launch_bounds__(512, 2)
void proj_kernel(const float* __restrict__ x,
                 const bf16_t* __restrict__ Wh, const bf16_t* __restrict__ Wl,
                 const float* __restrict__ bq, const float* __restrict__ bk,
                 const float* __restrict__ bv, const bf16_t* __restrict__ Rt,
                 bf16_t* __restrict__ q_ws, bf16_t* __restrict__ k2_ws,
                 bf16_t* __restrict__ vt2_ws)
{
    const int bx = blockIdx.x;
    const int b  = bx >> 6;
    const int h  = bx & 63;
    const int p0 = h * 64;
    const int n  = h & 3;
    const int h2 = h >> 2;
    const int bn = b * 4 + n;
    const int tid = threadIdx.x;

    __shared__ __align__(16) char SM[65536];

    {
        const int cpair = tid & 127, pg = tid >> 7;
        const int c0 = cpair * 2;
        const float* x0 = x + ((size_t)b * 256 + c0) * 4096 + p0 + pg * 16;
        const int sub = (c0 >> 6) * 128;
        const int u   = (c0 >> 3) & 7;
        const int e2  = (c0 & 7) * 2;
        #pragma unroll
        for (int i4 = 0; i4 < 4; ++i4) {
            f32x4 ra = *(const f32x4*)(x0 + i4 * 4);
            f32x4 rb = *(const f32x4*)(x0 + 4096 + i4 * 4);
            #pragma unroll
            for (int i = 0; i < 4; ++i) {
                const int p = pg * 16 + i4 * 4 + i;
                __bf16 ha = (__bf16)ra[i], hb = (__bf16)rb[i];
                float  la = ra[i] - (float)ha, lb = rb[i] - (float)hb;
                const int off = p * 512 + sub + ((u ^ (p & 7)) * 16) + e2;
                *(u32*)(SM + off)         = pack2(ha, hb);
                *(u32*)(SM + 32768 + off) = pack2((__bf16)la, (__bf16)lb);
            }
        }
    }
    __syncthreads();

    const int wid = tid >> 6, lane = tid & 63, l31 = lane & 31, hi = lane >> 5;

    int obs[3], pjs[3];
    const bf16_t* whp[3];
    const bf16_t* wlp[3];
    #pragma unroll
    for (int j = 0; j < 3; ++j) {
        const int of = (wid * 3 + j) * 32;
        pjs[j] = of >> 8;
        obs[j] = of & 255;
        whp[j] = Wh + (size_t)(of + l31) * 256 + hi * 8;
        wlp[j] = Wl + (size_t)(of + l31) * 256 + hi * 8;
    }

    const char* XHp = SM + l31 * 512;
    const char* XLp = SM + 32768 + l31 * 512;

    f32x16 acc[3][2] = {};

    #pragma unroll
    for (int ks = 0; ks < 16; ++ks) {
        bf16x8 wh[3], wl[3];
        #pragma unroll
        for (int j = 0; j < 3; ++j) {
            wh[j] = *(const bf16x8*)(whp[j] + ks * 16);
            wl[j] = *(const bf16x8*)(wlp[j] + ks * 16);
        }
        const int rb_ = (ks >> 2) * 128 + ((((ks * 2 + hi) & 7) ^ (l31 & 7)) * 16);
        bf16x8 xh[2], xl[2];
        #pragma unroll
        for (int pt = 0; pt < 2; ++pt) {
            xh[pt] = *(const bf16x8*)(XHp + pt * 16384 + rb_);
            xl[pt] = *(const bf16x8*)(XLp + pt * 16384 + rb_);
        }
        #pragma unroll
        for (int j = 0; j < 3; ++j)
            #pragma unroll
            for (int pt = 0; pt < 2; ++pt) {
                acc[j][pt] = __builtin_amdgcn_mfma_f32_32x32x16_bf16(wh[j], xh[pt], acc[j][pt], 0, 0, 0);
                acc[j][pt] = __builtin_amdgcn_mfma_f32_32x32x16_bf16(wh[j], xl[pt], acc[j][pt], 0, 0, 0);
                acc[j][pt] = __builtin_amdgcn_mfma_f32_32x32x16_bf16(wl[j], xh[pt], acc[j][pt], 0, 0, 0);
            }
    }
    __syncthreads();

    f32x4 bias[3][2][4];
    #pragma unroll
    for (int j = 0; j < 3; ++j) {
        const float* bp = pjs[j] == 0 ? bq : (pjs[j] == 1 ? bk : bv);
        #pragma unroll
        for (int g2 = 0; g2 < 4; ++g2) {
            f32x4 v = *(const f32x4*)(bp + obs[j] + hi * 4 + g2 * 8);
            if (pjs[j] == 0) {
                #pragma unroll
                for (int i = 0; i < 4; ++i) v[i] *= LOG2E;
            }
            bias[j][0][g2] = v;  bias[j][1][g2] = v;
        }
    }

    // pass 1: Q -> [0,32K), V -> [32,64K)
    #pragma unroll
    for (int j = 0; j < 3; ++j) {
        if (pjs[j] == 1) continue;
        #pragma unroll
        for (int pt = 0; pt < 2; ++pt) {
            const int d = pt * 32 + l31;
            #pragma unroll
            for (int g2 = 0; g2 < 4; ++g2)
                #pragma unroll
                for (int rr = 0; rr < 4; ++rr) {
                    const int o = obs[j] + rr + 4 * hi + 8 * g2;
                    const float v = acc[j][pt][g2 * 4 + rr] + bias[j][pt][g2][rr];
                    if (pjs[j] == 0) {
                        *(bf16_t*)(SM + o * 128 + d * 2) = (bf16_t)v;
                    } else {
                        *(bf16_t*)(SM + 32768 + d * 512 + ((o * 2) ^ ((d & 7) << 4))) = (bf16_t)v;
                    }
                }
        }
    }
    __syncthreads();
    {
        bf16_t* qp = q_ws + (size_t)bn * 4096 * 64;
        #pragma unroll
        for (int i = 0; i < 4; ++i) {
            const int c = i * 512 + tid;
            const int o = c >> 3, d8 = c & 7;
            uint4 v = *(const uint4*)(SM + c * 16);
            *(uint4*)(qp + (size_t)(o * 16 + h2) * 64 + d8 * 8) = v;
        }
        bf16_t* vp = vt2_ws + (size_t)bn * 64 * 4096 + h2 * 256;
        #pragma unroll
        for (int i = 0; i < 4; ++i) {
            const int c = i * 512 + tid;
            const int d = c >> 5, k = c & 31;
            uint4 v = *(const uint4*)(SM + 32768 + d * 512 + ((k * 16) ^ ((d & 7) << 4)));
            *(uint4*)(vp + (size_t)d * 4096 + k * 8) = v;
        }
    }
    __syncthreads();

    // pass 2: K -> [0,32K)
    #pragma unroll
    for (int j = 0; j < 3; ++j) {
        if (pjs[j] != 1) continue;
        #pragma unroll
        for (int pt = 0; pt < 2; ++pt) {
            const int d = pt * 32 + l31;
            #pragma unroll
            for (int g2 = 0; g2 < 4; ++g2)
                #pragma unroll
                for (int rr = 0; rr < 4; ++rr) {
                    const int o = obs[j] + rr + 4 * hi + 8 * g2;
                    *(bf16_t*)(SM + o * 128 + d * 2) =
                        (bf16_t)(acc[j][pt][g2 * 4 + rr] + bias[j][pt][g2][rr]);
                }
        }
    }
    __syncthreads();
    {
        const bf16_t* Rp = Rt + ((size_t)n * 4096 + h2 * 256) * 64;
        bf16_t* kp = k2_ws + ((size_t)bn * 4096 + h2 * 256) * 64;
        #pragma unroll
        for (int i = 0; i < 4; ++i) {
            const int c = i * 512 + tid;
            bf16x8 kv = *(const bf16x8*)(SM + c * 16);
            bf16x8 rv = *(const bf16x8*)(Rp + c * 8);
            bf16x8 res;
            #pragma unroll
            for (int ii = 0; ii < 8; ++ii)
                res[ii] = (__bf16)((float)kv[ii] + (float)rv[ii]);
            *(bf16x8*)(kp + c * 8) = res;
        }
    }
}

// =======================================================================================
// flash attention, LDS DMA ring. SPLIT=1: each block does 32 KV tiles (half), ring-2
// (32KB LDS) -> 4 blocks/CU = 16 waves/CU, un-normalized f32 partials + lsum.
// SPLIT=0 fallback: 64 tiles, ring-4 (64KB), normalized output (proven R5 scheme).
// =======================================================================================
template<int SPLIT>
__global__ __launch_bounds__(256, SPLIT ? 4 : 2)
void attn_kernel(const bf16_t* __restrict__ q_ws, const bf16_t* __restrict__ k_ws,
                 const bf16_t* __restrict__ vt_ws, float* __restrict__ O0,
                 float* __restrict__ L0, float* __restrict__ L1,
                 float* __restrict__ out)
{
    constexpr int RING = SPLIT ? 2 : 4;
    const int tid  = threadIdx.x;
    const int wid  = tid >> 6;
    const int lane = tid & 63;
    const int l31  = lane & 31;
    const int hi   = lane >> 5;

    int bn, qb, half;
    if (SPLIT) {
        const int wg  = blockIdx.x;                 // 1024 blocks
        const int swz = (wg & 7) * 128 + (wg >> 3); // 128/XCD = 2 bn
        bn = swz >> 6;
        const int r = swz & 63;
        qb = r >> 1;
        half = r & 1;
    } else {
        const int wg  = blockIdx.x;                 // 512 blocks
        const int swz = (wg & 7) * 64 + (wg >> 3);
        bn = swz >> 5;
        qb = swz & 31;
        half = 0;
    }
    const int tbase = SPLIT ? half * 32 : 0;
    const int b = bn >> 2, n = bn & 3;

    __shared__ __align__(16) bf16_t Kt[RING][64 * 64];
    __shared__ __align__(16) bf16_t Vt[RING][64 * 64];

    const bf16_t* Qb = q_ws  + (size_t)bn * S_SZ * HS;
    const bf16_t* Kb = k_ws  + (size_t)bn * S_SZ * HS;
    const bf16_t* Vb = vt_ws + (size_t)bn * HS * S_SZ;

    const int c0 = wid * 64 + lane;
    const int ra = c0 >> 3, ga = (c0 & 7) ^ (ra & 7);
    const bf16_t* ksrcA = Kb + ra * HS + ga * 8;
    const bf16_t* ksrcB = ksrcA + 32 * HS;
    const bf16_t* vsrcA = Vb + (size_t)ra * S_SZ + ga * 8;
    const bf16_t* vsrcB = vsrcA + (size_t)32 * S_SZ;

#define STAGE(buf, ts)                                                        \
    GLOAD_LDS(ksrcA + (size_t)(ts) * 64 * HS, &Kt[buf][wid * 512]);           \
    GLOAD_LDS(ksrcB + (size_t)(ts) * 64 * HS, &Kt[buf][2048 + wid * 512]);    \
    GLOAD_LDS(vsrcA + (ts) * 64,              &Vt[buf][wid * 512]);           \
    GLOAD_LDS(vsrcB + (ts) * 64,              &Vt[buf][2048 + wid * 512]);

    const int q = qb * 128 + wid * 32 + l31;
    bf16x8 qf[4];
    #pragma unroll
    for (int dk = 0; dk < 4; ++dk)
        qf[dk] = *(const bf16x8*)(Qb + (size_t)q * HS + dk * 16 + hi * 8);

    f32x16 oacc[2];
    f32x16 Z16;
    #pragma unroll
    for (int i = 0; i < 16; ++i) { oacc[0][i] = 0.f; oacc[1][i] = 0.f; Z16[i] = 0.f; }
    float lsum = 0.f;

    const int swzme = (l31 & 7) << 4;

#define TILE(BUF)                                                                      \
    { const char* Kb_ = (const char*)&Kt[BUF][0] + l31 * 128;                          \
      const char* Vb_ = (const char*)&Vt[BUF][0] + l31 * 128;                          \
      f32x16 sacc[2];                                                                  \
      __builtin_amdgcn_s_setprio(1);                                                   \
      _Pragma("unroll")                                                                \
      for (int hh = 0; hh < 2; ++hh) {                                                 \
          bf16x8 kf[4];                                                                \
          _Pragma("unroll")                                                            \
          for (int dk = 0; dk < 4; ++dk)                                               \
              kf[dk] = *(const bf16x8*)(Kb_ + hh * 4096 + (((2 * dk + hi) * 16) ^ swzme)); \
          sacc[hh] = __builtin_amdgcn_mfma_f32_32x32x16_bf16(kf[0], qf[0], Z16, 0, 0, 0);  \
          _Pragma("unroll")                                                            \
          for (int dk = 1; dk < 4; ++dk)                                               \
              sacc[hh] = __builtin_amdgcn_mfma_f32_32x32x16_bf16(kf[dk], qf[dk], sacc[hh], 0, 0, 0); \
      }                                                                                \
      __builtin_amdgcn_s_setprio(0);                                                   \
      u32 Wd[2][4][2];                                                                 \
      float ps[4] = {0.f, 0.f, 0.f, 0.f};                                              \
      _Pragma("unroll")                                                                \
      for (int hh = 0; hh < 2; ++hh)                                                   \
      _Pragma("unroll")                                                                \
      for (int c = 0; c < 4; ++c)                                                      \
      _Pragma("unroll")                                                                \
      for (int tt = 0; tt < 2; ++tt) {                                                 \
          float pa = __builtin_amdgcn_exp2f(sacc[hh][c * 4 + tt * 2]);                 \
          float pb = __builtin_amdgcn_exp2f(sacc[hh][c * 4 + tt * 2 + 1]);             \
          ps[c] += pa + pb;                                                            \
          u32 w_;                                                                      \
          asm("v_cvt_pk_bf16_f32 %0, %1, %2" : "=v"(w_) : "v"(pa), "v"(pb));           \
          Wd[hh][c][tt] = w_; }                                                        \
      lsum += (ps[0] + ps[1]) + (ps[2] + ps[3]);                                       \
      u32 F[4][4];                                                                     \
      _Pragma("unroll")                                                                \
      for (int hh = 0; hh < 2; ++hh)                                                   \
      _Pragma("unroll")                                                                \
      for (int pr = 0; pr < 2; ++pr)                                                   \
      _Pragma("unroll")                                                                \
      for (int tt = 0; tt < 2; ++tt) {                                                 \
          u32 a_ = Wd[hh][2 * pr][tt], b_ = Wd[hh][2 * pr + 1][tt];                    \
          asm("v_permlane32_swap_b32 %0, %1" : "+v"(a_), "+v"(b_));                    \
          F[2 * hh + pr][tt]     = a_;                                                 \
          F[2 * hh + pr][2 + tt] = b_; }                                               \
      __builtin_amdgcn_s_setprio(1);                                                   \
      _Pragma("unroll")                                                                \
      for (int dh = 0; dh < 2; ++dh)                                                   \
      _Pragma("unroll")                                                                \
      for (int kk = 0; kk < 4; ++kk) {                                                 \
          bf16x8 vf = *(const bf16x8*)(Vb_ + dh * 4096 + (((2 * kk + hi) * 16) ^ swzme)); \
          union { u32 u[4]; bf16x8 v; } pf;                                            \
          pf.u[0] = F[kk][0]; pf.u[1] = F[kk][1]; pf.u[2] = F[kk][2]; pf.u[3] = F[kk][3]; \
          oacc[dh] = __builtin_amdgcn_mfma_f32_32x32x16_bf16(vf, pf.v, oacc[dh], 0, 0, 0); } \
      __builtin_amdgcn_s_setprio(0); }

    if (SPLIT) {
        // ring-2, depth-1: stage(t+1) during compute(t); vmcnt(0) stall ~0
        STAGE(0, tbase);
        asm volatile("s_waitcnt vmcnt(0)" ::: "memory");
        __builtin_amdgcn_s_barrier();
        asm volatile("" ::: "memory");
        for (int t = 0; t < 32; t += 2) {
            { const int ts = tbase + ((t + 1 < 32) ? t + 1 : 31); STAGE(1, ts); }
            TILE(0);
            asm volatile("s_waitcnt vmcnt(0)" ::: "memory");
            __builtin_amdgcn_s_barrier();
            asm volatile("" ::: "memory");
            { const int ts = tbase + ((t + 2 < 32) ? t + 2 : 31); STAGE(0, ts); }
            TILE(1);
            asm volatile("s_waitcnt vmcnt(0)" ::: "memory");
            __builtin_amdgcn_s_barrier();
            asm volatile("" ::: "memory");
        }
    } else {
        // ring-4, depth-3 (proven R5/R6 scheme)
        STAGE(0, 0); STAGE(1, 1); STAGE(2, 2);
        asm volatile("s_waitcnt vmcnt(8)" ::: "memory");
        __builtin_amdgcn_s_barrier();
        asm volatile("" ::: "memory");
        for (int tb = 0; tb < 64; tb += 4) {
            #pragma unroll
            for (int u = 0; u < 4; ++u) {
                const int t = tb + u;
                { const int ts = (t + 3 > 63) ? 63 : t + 3; STAGE((u + 3) & 3, ts); }
                TILE(u & (RING - 1));
                asm volatile("s_waitcnt vmcnt(4)" ::: "memory");
                __builtin_amdgcn_s_barrier();
                asm volatile("" ::: "memory");
            }
        }
    }
#undef TILE
#undef STAGE

    // ---- epilogue ----
    float lt = lsum + __shfl_xor(lsum, 32);
    if (SPLIT) {
        float* Otgt = half ? out : O0;
        float* outp = Otgt + (size_t)b * OUT_B_STRIDE + (size_t)q * 256 + n * 64;
        #pragma unroll
        for (int dh = 0; dh < 2; ++dh)
            #pragma unroll
            for (int g2 = 0; g2 < 4; ++g2) {
                f32x4 v4;
                #pragma unroll
                for (int r = 0; r < 4; ++r) v4[r] = oacc[dh][g2 * 4 + r];
                *(f32x4*)(outp + dh * 32 + g2 * 8 + hi * 4) = v4;
            }
        if (hi == 0) (half ? L1 : L0)[bn * 4096 + q] = lt;
    } else {
        float inv = 1.0f / lt;
        float* outp = out + (size_t)b * OUT_B_STRIDE + (size_t)q * 256 + n * 64;
        #pragma unroll
        for (int dh = 0; dh < 2; ++dh)
            #pragma unroll
            for (int g2 = 0; g2 < 4; ++g2) {
                f32x4 v4;
                #pragma unroll
                for (int r = 0; r < 4; ++r) v4[r] = oacc[dh][g2 * 4 + r] * inv;
                *(f32x4*)(outp + dh * 32 + g2 * 8 + hi * 4) = v4;
            }
    }
}

// =======================================================================================
// combine: out = (O0 + out) / (L0 + L1). 2048 x 256 x 8 f32 = 4M elements.
// =======================================================================================
__global__ __launch_bounds__(256)
void combine_kernel(const float* __restrict__ O0, const float* __restrict__ L0,
                    const float* __restrict__ L1, float* __restrict__ out)
{
    const int i = (blockIdx.x * 256 + threadIdx.x) * 8;
    const int s = (i >> 8) & 4095;
    const int b = i >> 20;
    const int n = (i >> 6) & 3;
    const int li = (b * 4 + n) * 4096 + s;
    const float inv = 1.0f / (L0[li] + L1[li]);
    f32x4 a0 = *(const f32x4*)(O0 + i);
    f32x4 a1 = *(const f32x4*)(out + i);
    f32x4 b0 = *(const f32x4*)(O0 + i + 4);
    f32x4 b1 = *(const f32x4*)(out + i + 4);
    f32x4 r0, r1;
    #pragma unroll
    for (int k = 0; k < 4; ++k) {
        r0[k] = (a0[k] + a1[k]) * inv;
        r1[k] = (b0[k] + b1[k]) * inv;
    }
    *(f32x4*)(out + i)     = r0;
    *(f32x4*)(out + i + 4) = r1;
}

extern "C" void kernel_launch(void* const* d_in, const int* in_sizes, int n_in,
                              void* d_out, int out_size, void* d_ws, size_t ws_size,
                              hipStream_t stream)
{
    const float* x     = (const float*)d_in[0];
    const float* wq    = (const float*)d_in[1];
    const float* bq    = (const float*)d_in[2];
    const float* wk    = (const float*)d_in[3];
    const float* bk    = (const float*)d_in[4];
    const float* wv    = (const float*)d_in[5];
    const float* bv    = (const float*)d_in[6];
    const float* rel_h = (const float*)d_in[7];
    const float* rel_w = (const float*)d_in[8];
    float* out = (float*)d_out;

    bf16_t* q_ws   = (bf16_t*)d_ws;
    bf16_t* k2_ws  = q_ws  + (size_t)16 * S_SZ * HS;      // +8MB
    bf16_t* vt2_ws = k2_ws + (size_t)16 * S_SZ * HS;      // +16MB
    float*  O0     = (float*)((char*)d_ws + 25165824);    // 16MB
    float*  L0     = (float*)((char*)d_ws + 41943040);    // 256KB
    float*  L1     = (float*)((char*)d_ws + 42205184);    // 256KB
    const size_t need = 42467328;

    // W hi/lo + R table scratch in d_out's tail (dead after proj; attn overwrites out)
    bf16_t* end = (bf16_t*)d_out + (size_t)out_size * 2;
    bf16_t* Wl  = end - 196608;
    bf16_t* Wh  = Wl - 196608;
    bf16_t* Rt  = Wh - 1048576;

    prep_kernel<<<112, 256, 0, stream>>>(wq, wk, wv, rel_h, rel_w, Wh, Wl, Rt);
    proj_kernel<<<256, 512, 0, stream>>>(x, Wh, Wl, bq, bk, bv, Rt,
                                         q_ws, k2_ws, vt2_ws);
    if (ws_size >= need) {
        attn_kernel<1><<<1024, 256, 0, stream>>>(q_ws, k2_ws, vt2_ws, O0, L0, L1, out);
        combine_kernel<<<2048, 256, 0, stream>>>(O0, L0, L1, out);
    } else {
        attn_kernel<0><<<512, 256, 0, stream>>>(q_ws, k2_ws, vt2_ws, O0, L0, L1, out);
    }
}

// Round 9
// 127.674 us; speedup vs baseline: 2.1566x; 1.0792x over previous
//
#include <hip/hip_runtime.h>
#include <hip/hip_bf16.h>
#include <stdint.h>
#include <math.h>

typedef __bf16 bf16_t;
typedef __bf16 bf16x8 __attribute__((ext_vector_type(8)));
typedef float  f32x4  __attribute__((ext_vector_type(4)));
typedef float  f32x16 __attribute__((ext_vector_type(16)));
typedef unsigned int u32;

#define S_SZ 4096
#define HS   64
#define OUT_B_STRIDE (256 * 64 * 64)
#define LOG2E 1.4426950408889634f

// async global->LDS, 16B per lane, dest = wave-uniform base + lane*16
#define GLOAD_LDS(gsrc, ldst)                                                              \
    __builtin_amdgcn_global_load_lds((__attribute__((address_space(1))) void*)(void*)(gsrc), \
                                     (__attribute__((address_space(3))) void*)(void*)(ldst),  \
                                     16, 0, 0)

static __device__ __forceinline__ u32 pack2(__bf16 a, __bf16 b) {
    return (u32)__builtin_bit_cast(uint16_t, a) | ((u32)__builtin_bit_cast(uint16_t, b) << 16);
}

// =======================================================================================
// prep: blocks 0..47: W -> bf16 hi/lo (Q rows pre-scaled by log2e), coalesced.
//       blocks 48..111: R[n][t][d] = rel_h + rel_w (bf16), t = h2*256 + o, LDS-staged.
// =======================================================================================
__global__ __launch_bounds__(256)
void prep_kernel(const float* __restrict__ wq, const float* __restrict__ wk,
                 const float* __restrict__ wv, const float* __restrict__ rel_h,
                 const float* __restrict__ rel_w,
                 bf16_t* __restrict__ Wh, bf16_t* __restrict__ Wl,
                 bf16_t* __restrict__ Rt)
{
    const int blk = blockIdx.x;
    if (blk < 48) {
        const int base = blk * 4096;
        #pragma unroll
        for (int i = 0; i < 16; ++i) {
            const int e = base + i * 256 + threadIdx.x;
            const int o = e >> 8, c = e & 255;
            const float* src = o < 256 ? wq : (o < 512 ? wk : wv);
            float v = src[(size_t)(o & 255) * 256 + c];
            if (o < 256) v *= LOG2E;
            __bf16 h = (__bf16)v;
            Wh[e] = h;
            Wl[e] = (__bf16)(v - (float)h);
        }
    } else {
        const int rb = blk - 48;
        const int n = rb >> 4, h2 = rb & 15;
        __shared__ float rh[4096], rw[4096];
        for (int i = threadIdx.x; i < 4096; i += 256) {
            rh[i] = rel_h[n * 4096 + i];
            rw[i] = rel_w[n * 4096 + i];
        }
        __syncthreads();
        bf16_t* Rp = Rt + ((size_t)n * 4096 + h2 * 256) * 64;
        const int d0 = (threadIdx.x & 7) * 8;
        const int ob = threadIdx.x >> 3;
        #pragma unroll
        for (int i = 0; i < 8; ++i) {
            const int o  = i * 32 + ob;
            const int ih = (o & 3) * 16 + h2;
            const int iw = o >> 2;
            bf16x8 rv;
            #pragma unroll
            for (int dd = 0; dd < 8; ++dd)
                rv[dd] = (bf16_t)(rh[(d0 + dd) * 64 + ih] + rw[(d0 + dd) * 64 + iw]);
            *(bf16x8*)(Rp + (size_t)o * 64 + d0) = rv;
        }
    }
}

// =======================================================================================
// proj (64KB LDS): bf16 MFMA, 3-product hi/lo split, W register double-buffer
// (prefetch ks+1's W frags a full MFMA-burst ahead), two-pass coalesced epilogue.
// grid 256, block 512 (8 waves).
// =======================================================================================
__global__ __launch_bounds__(512, 2)
void proj_kernel(const float* __restrict__ x,
                 const bf16_t* __restrict__ Wh, const bf16_t* __restrict__ Wl,
                 const float* __restrict__ bq, const float* __restrict__ bk,
                 const float* __restrict__ bv, const bf16_t* __restrict__ Rt,
                 bf16_t* __restrict__ q_ws, bf16_t* __restrict__ k2_ws,
                 bf16_t* __restrict__ vt2_ws)
{
    const int bx = blockIdx.x;
    const int b  = bx >> 6;
    const int h  = bx & 63;
    const int p0 = h * 64;
    const int n  = h & 3;
    const int h2 = h >> 2;
    const int bn = b * 4 + n;
    const int tid = threadIdx.x;

    __shared__ __align__(16) char SM[65536];

    {
        const int cpair = tid & 127, pg = tid >> 7;
        const int c0 = cpair * 2;
        const float* x0 = x + ((size_t)b * 256 + c0) * 4096 + p0 + pg * 16;
        const int sub = (c0 >> 6) * 128;
        const int u   = (c0 >> 3) & 7;
        const int e2  = (c0 & 7) * 2;
        #pragma unroll
        for (int i4 = 0; i4 < 4; ++i4) {
            f32x4 ra = *(const f32x4*)(x0 + i4 * 4);
            f32x4 rb = *(const f32x4*)(x0 + 4096 + i4 * 4);
            #pragma unroll
            for (int i = 0; i < 4; ++i) {
                const int p = pg * 16 + i4 * 4 + i;
                __bf16 ha = (__bf16)ra[i], hb = (__bf16)rb[i];
                float  la = ra[i] - (float)ha, lb = rb[i] - (float)hb;
                const int off = p * 512 + sub + ((u ^ (p & 7)) * 16) + e2;
                *(u32*)(SM + off)         = pack2(ha, hb);
                *(u32*)(SM + 32768 + off) = pack2((__bf16)la, (__bf16)lb);
            }
        }
    }
    __syncthreads();

    const int wid = tid >> 6, lane = tid & 63, l31 = lane & 31, hi = lane >> 5;

    int obs[3], pjs[3];
    const bf16_t* whp[3];
    const bf16_t* wlp[3];
    #pragma unroll
    for (int j = 0; j < 3; ++j) {
        const int of = (wid * 3 + j) * 32;
        pjs[j] = of >> 8;
        obs[j] = of & 255;
        whp[j] = Wh + (size_t)(of + l31) * 256 + hi * 8;
        wlp[j] = Wl + (size_t)(of + l31) * 256 + hi * 8;
    }

    const char* XHp = SM + l31 * 512;
    const char* XLp = SM + 32768 + l31 * 512;

    f32x16 acc[3][2] = {};

    // W register double-buffer: prefetch ks+1 while MFMA'ing ks
    bf16x8 whC[3], wlC[3], whN[3], wlN[3];
    #pragma unroll
    for (int j = 0; j < 3; ++j) {
        whC[j] = *(const bf16x8*)(whp[j]);
        wlC[j] = *(const bf16x8*)(wlp[j]);
    }

    #pragma unroll
    for (int ks = 0; ks < 16; ++ks) {
        if (ks < 15) {
            #pragma unroll
            for (int j = 0; j < 3; ++j) {
                whN[j] = *(const bf16x8*)(whp[j] + (ks + 1) * 16);
                wlN[j] = *(const bf16x8*)(wlp[j] + (ks + 1) * 16);
            }
        }
        const int rb_ = (ks >> 2) * 128 + ((((ks * 2 + hi) & 7) ^ (l31 & 7)) * 16);
        bf16x8 xh[2], xl[2];
        #pragma unroll
        for (int pt = 0; pt < 2; ++pt) {
            xh[pt] = *(const bf16x8*)(XHp + pt * 16384 + rb_);
            xl[pt] = *(const bf16x8*)(XLp + pt * 16384 + rb_);
        }
        #pragma unroll
        for (int j = 0; j < 3; ++j)
            #pragma unroll
            for (int pt = 0; pt < 2; ++pt) {
                acc[j][pt] = __builtin_amdgcn_mfma_f32_32x32x16_bf16(whC[j], xh[pt], acc[j][pt], 0, 0, 0);
                acc[j][pt] = __builtin_amdgcn_mfma_f32_32x32x16_bf16(whC[j], xl[pt], acc[j][pt], 0, 0, 0);
                acc[j][pt] = __builtin_amdgcn_mfma_f32_32x32x16_bf16(wlC[j], xh[pt], acc[j][pt], 0, 0, 0);
            }
        #pragma unroll
        for (int j = 0; j < 3; ++j) { whC[j] = whN[j]; wlC[j] = wlN[j]; }
    }
    __syncthreads();

    f32x4 bias[3][2][4];
    #pragma unroll
    for (int j = 0; j < 3; ++j) {
        const float* bp = pjs[j] == 0 ? bq : (pjs[j] == 1 ? bk : bv);
        #pragma unroll
        for (int g2 = 0; g2 < 4; ++g2) {
            f32x4 v = *(const f32x4*)(bp + obs[j] + hi * 4 + g2 * 8);
            if (pjs[j] == 0) {
                #pragma unroll
                for (int i = 0; i < 4; ++i) v[i] *= LOG2E;
            }
            bias[j][0][g2] = v;  bias[j][1][g2] = v;
        }
    }

    // pass 1: Q -> [0,32K), V -> [32,64K)
    #pragma unroll
    for (int j = 0; j < 3; ++j) {
        if (pjs[j] == 1) continue;
        #pragma unroll
        for (int pt = 0; pt < 2; ++pt) {
            const int d = pt * 32 + l31;
            #pragma unroll
            for (int g2 = 0; g2 < 4; ++g2)
                #pragma unroll
                for (int rr = 0; rr < 4; ++rr) {
                    const int o = obs[j] + rr + 4 * hi + 8 * g2;
                    const float v = acc[j][pt][g2 * 4 + rr] + bias[j][pt][g2][rr];
                    if (pjs[j] == 0) {
                        *(bf16_t*)(SM + o * 128 + d * 2) = (bf16_t)v;
                    } else {
                        *(bf16_t*)(SM + 32768 + d * 512 + ((o * 2) ^ ((d & 7) << 4))) = (bf16_t)v;
                    }
                }
        }
    }
    __syncthreads();
    {
        bf16_t* qp = q_ws + (size_t)bn * 4096 * 64;
        #pragma unroll
        for (int i = 0; i < 4; ++i) {
            const int c = i * 512 + tid;
            const int o = c >> 3, d8 = c & 7;
            uint4 v = *(const uint4*)(SM + c * 16);
            *(uint4*)(qp + (size_t)(o * 16 + h2) * 64 + d8 * 8) = v;
        }
        bf16_t* vp = vt2_ws + (size_t)bn * 64 * 4096 + h2 * 256;
        #pragma unroll
        for (int i = 0; i < 4; ++i) {
            const int c = i * 512 + tid;
            const int d = c >> 5, k = c & 31;
            uint4 v = *(const uint4*)(SM + 32768 + d * 512 + ((k * 16) ^ ((d & 7) << 4)));
            *(uint4*)(vp + (size_t)d * 4096 + k * 8) = v;
        }
    }
    __syncthreads();

    // pass 2: K -> [0,32K)
    #pragma unroll
    for (int j = 0; j < 3; ++j) {
        if (pjs[j] != 1) continue;
        #pragma unroll
        for (int pt = 0; pt < 2; ++pt) {
            const int d = pt * 32 + l31;
            #pragma unroll
            for (int g2 = 0; g2 < 4; ++g2)
                #pragma unroll
                for (int rr = 0; rr < 4; ++rr) {
                    const int o = obs[j] + rr + 4 * hi + 8 * g2;
                    *(bf16_t*)(SM + o * 128 + d * 2) =
                        (bf16_t)(acc[j][pt][g2 * 4 + rr] + bias[j][pt][g2][rr]);
                }
        }
    }
    __syncthreads();
    {
        const bf16_t* Rp = Rt + ((size_t)n * 4096 + h2 * 256) * 64;
        bf16_t* kp = k2_ws + ((size_t)bn * 4096 + h2 * 256) * 64;
        #pragma unroll
        for (int i = 0; i < 4; ++i) {
            const int c = i * 512 + tid;
            bf16x8 kv = *(const bf16x8*)(SM + c * 16);
            bf16x8 rv = *(const bf16x8*)(Rp + c * 8);
            bf16x8 res;
            #pragma unroll
            for (int ii = 0; ii < 8; ++ii)
                res[ii] = (__bf16)((float)kv[ii] + (float)rv[ii]);
            *(bf16x8*)(kp + c * 8) = res;
        }
    }
}

// =======================================================================================
// flash attention, T15 double-pipeline: iter t runs QK(t+1) [MFMA] || exp(t) [VALU]
// || PV(t) [MFMA]. 4-buffer ring, counted vmcnt(4) at loop top, 1 barrier/iter.
// grid 512 (16 bn x 32 qb), block 256 = 4 waves, 2 blocks/CU.
// =======================================================================================
__global__ __launch_bounds__(256, 2)
void attn_kernel(const bf16_t* __restrict__ q_ws, const bf16_t* __restrict__ k_ws,
                 const bf16_t* __restrict__ vt_ws, float* __restrict__ out)
{
    const int tid  = threadIdx.x;
    const int wid  = tid >> 6;
    const int lane = tid & 63;
    const int l31  = lane & 31;
    const int hi   = lane >> 5;

    // bijective XCD swizzle: each XCD gets 64 consecutive swz = 2 bn
    const int wg  = blockIdx.x;
    const int swz = (wg & 7) * 64 + (wg >> 3);
    const int bn  = swz >> 5;
    const int qb  = swz & 31;
    const int b   = bn >> 2, n = bn & 3;

    __shared__ __align__(16) bf16_t Kt[4][64 * 64];   // [t][d], XOR-swizzled 16B units
    __shared__ __align__(16) bf16_t Vt[4][64 * 64];   // [d][t], XOR-swizzled

    const bf16_t* Qb = q_ws  + (size_t)bn * S_SZ * HS;
    const bf16_t* Kb = k_ws  + (size_t)bn * S_SZ * HS;
    const bf16_t* Vb = vt_ws + (size_t)bn * HS * S_SZ;

    const int c0 = wid * 64 + lane;
    const int ra = c0 >> 3, ga = (c0 & 7) ^ (ra & 7);
    const bf16_t* ksrcA = Kb + ra * HS + ga * 8;
    const bf16_t* ksrcB = ksrcA + 32 * HS;
    const bf16_t* vsrcA = Vb + (size_t)ra * S_SZ + ga * 8;
    const bf16_t* vsrcB = vsrcA + (size_t)32 * S_SZ;

#define STAGE(buf, ts)                                                        \
    GLOAD_LDS(ksrcA + (size_t)(ts) * 64 * HS, &Kt[buf][wid * 512]);           \
    GLOAD_LDS(ksrcB + (size_t)(ts) * 64 * HS, &Kt[buf][2048 + wid * 512]);    \
    GLOAD_LDS(vsrcA + (ts) * 64,              &Vt[buf][wid * 512]);           \
    GLOAD_LDS(vsrcB + (ts) * 64,              &Vt[buf][2048 + wid * 512]);

    const int q = qb * 128 + wid * 32 + l31;
    bf16x8 qf[4];
    #pragma unroll
    for (int dk = 0; dk < 4; ++dk)
        qf[dk] = *(const bf16x8*)(Qb + (size_t)q * HS + dk * 16 + hi * 8);

    f32x16 oacc[2];
    f32x16 Z16;
    #pragma unroll
    for (int i = 0; i < 16; ++i) { oacc[0][i] = 0.f; oacc[1][i] = 0.f; Z16[i] = 0.f; }
    float lsum = 0.f;

    const int swzme = (l31 & 7) << 4;

#define QKPAIR(DST, BUF)                                                               \
    { const char* Kb_ = (const char*)&Kt[BUF][0] + l31 * 128;                          \
      __builtin_amdgcn_s_setprio(1);                                                   \
      _Pragma("unroll")                                                                \
      for (int hh = 0; hh < 2; ++hh) {                                                 \
          bf16x8 kf[4];                                                                \
          _Pragma("unroll")                                                            \
          for (int dk = 0; dk < 4; ++dk)                                               \
              kf[dk] = *(const bf16x8*)(Kb_ + hh * 4096 + (((2 * dk + hi) * 16) ^ swzme)); \
          DST[hh] = __builtin_amdgcn_mfma_f32_32x32x16_bf16(kf[0], qf[0], Z16, 0, 0, 0);   \
          _Pragma("unroll")                                                            \
          for (int dk = 1; dk < 4; ++dk)                                               \
              DST[hh] = __builtin_amdgcn_mfma_f32_32x32x16_bf16(kf[dk], qf[dk], DST[hh], 0, 0, 0); \
      }                                                                                \
      __builtin_amdgcn_s_setprio(0); }

#define EXPPV(SRC, VBUF)                                                               \
    { u32 Wd[2][4][2];                                                                 \
      float ps[4] = {0.f, 0.f, 0.f, 0.f};                                              \
      _Pragma("unroll")                                                                \
      for (int hh = 0; hh < 2; ++hh)                                                   \
      _Pragma("unroll")                                                                \
      for (int c = 0; c < 4; ++c)                                                      \
      _Pragma("unroll")                                                                \
      for (int tt = 0; tt < 2; ++tt) {                                                 \
          float pa = __builtin_amdgcn_exp2f(SRC[hh][c * 4 + tt * 2]);                  \
          float pb = __builtin_amdgcn_exp2f(SRC[hh][c * 4 + tt * 2 + 1]);              \
          ps[c] += pa + pb;                                                            \
          u32 w_;                                                                      \
          asm("v_cvt_pk_bf16_f32 %0, %1, %2" : "=v"(w_) : "v"(pa), "v"(pb));           \
          Wd[hh][c][tt] = w_; }                                                        \
      lsum += (ps[0] + ps[1]) + (ps[2] + ps[3]);                                       \
      u32 F[4][4];                                                                     \
      _Pragma("unroll")                                                                \
      for (int hh = 0; hh < 2; ++hh)                                                   \
      _Pragma("unroll")                                                                \
      for (int pr = 0; pr < 2; ++pr)                                                   \
      _Pragma("unroll")                                                                \
      for (int tt = 0; tt < 2; ++tt) {                                                 \
          u32 a_ = Wd[hh][2 * pr][tt], b_ = Wd[hh][2 * pr + 1][tt];                    \
          asm("v_permlane32_swap_b32 %0, %1" : "+v"(a_), "+v"(b_));                    \
          F[2 * hh + pr][tt]     = a_;                                                 \
          F[2 * hh + pr][2 + tt] = b_; }                                               \
      const char* Vb_ = (const char*)&Vt[VBUF][0] + l31 * 128;                         \
      __builtin_amdgcn_s_setprio(1);                                                   \
      _Pragma("unroll")                                                                \
      for (int dh = 0; dh < 2; ++dh)                                                   \
      _Pragma("unroll")                                                                \
      for (int kk = 0; kk < 4; ++kk) {                                                 \
          bf16x8 vf = *(const bf16x8*)(Vb_ + dh * 4096 + (((2 * kk + hi) * 16) ^ swzme)); \
          union { u32 u[4]; bf16x8 v; } pf;                                            \
          pf.u[0] = F[kk][0]; pf.u[1] = F[kk][1]; pf.u[2] = F[kk][2]; pf.u[3] = F[kk][3]; \
          oacc[dh] = __builtin_amdgcn_mfma_f32_32x32x16_bf16(vf, pf.v, oacc[dh], 0, 0, 0); } \
      __builtin_amdgcn_s_setprio(0); }

#define ITER(U, SC, SN)                                                                \
    { asm volatile("s_waitcnt vmcnt(4)" ::: "memory");                                 \
      __builtin_amdgcn_s_barrier();                                                    \
      asm volatile("" ::: "memory");                                                   \
      { const int t_ = tb + (U);                                                       \
        const int ts_ = (t_ + 3 > 63) ? 63 : t_ + 3;                                   \
        STAGE(((U) + 3) & 3, ts_); }                                                   \
      QKPAIR(SN, ((U) + 1) & 3);                                                       \
      EXPPV(SC, (U) & 3); }

    // prologue: stage 0..2; QK(0)
    STAGE(0, 0); STAGE(1, 1); STAGE(2, 2);
    asm volatile("s_waitcnt vmcnt(8)" ::: "memory");
    __builtin_amdgcn_s_barrier();
    asm volatile("" ::: "memory");

    f32x16 S0[2], S1[2];
    QKPAIR(S0, 0);

    for (int tb = 0; tb < 64; tb += 4) {
        ITER(0, S0, S1);
        ITER(1, S1, S0);
        ITER(2, S0, S1);
        ITER(3, S1, S0);
    }
#undef ITER
#undef EXPPV
#undef QKPAIR
#undef STAGE

    // ---- epilogue ----
    float lt  = lsum + __shfl_xor(lsum, 32);
    float inv = 1.0f / lt;
    float* outp = out + (size_t)b * OUT_B_STRIDE + (size_t)q * 256 + n * 64;
    #pragma unroll
    for (int dh = 0; dh < 2; ++dh)
        #pragma unroll
        for (int g2 = 0; g2 < 4; ++g2) {
            f32x4 v4;
            #pragma unroll
            for (int r = 0; r < 4; ++r) v4[r] = oacc[dh][g2 * 4 + r] * inv;
            *(f32x4*)(outp + dh * 32 + g2 * 8 + hi * 4) = v4;
        }
}

extern "C" void kernel_launch(void* const* d_in, const int* in_sizes, int n_in,
                              void* d_out, int out_size, void* d_ws, size_t ws_size,
                              hipStream_t stream)
{
    const float* x     = (const float*)d_in[0];
    const float* wq    = (const float*)d_in[1];
    const float* bq    = (const float*)d_in[2];
    const float* wk    = (const float*)d_in[3];
    const float* bk    = (const float*)d_in[4];
    const float* wv    = (const float*)d_in[5];
    const float* bv    = (const float*)d_in[6];
    const float* rel_h = (const float*)d_in[7];
    const float* rel_w = (const float*)d_in[8];
    float* out = (float*)d_out;

    bf16_t* q_ws   = (bf16_t*)d_ws;
    bf16_t* k2_ws  = q_ws  + (size_t)16 * S_SZ * HS;
    bf16_t* vt2_ws = k2_ws + (size_t)16 * S_SZ * HS;

    // scratch in d_out's tail (dead after proj; attn overwrites all of out)
    bf16_t* end = (bf16_t*)d_out + (size_t)out_size * 2;
    bf16_t* Wl  = end - 196608;
    bf16_t* Wh  = Wl - 196608;
    bf16_t* Rt  = Wh - 1048576;

    prep_kernel<<<112, 256, 0, stream>>>(wq, wk, wv, rel_h, rel_w, Wh, Wl, Rt);
    proj_kernel<<<256, 512, 0, stream>>>(x, Wh, Wl, bq, bk, bv, Rt,
                                         q_ws, k2_ws, vt2_ws);
    attn_kernel<<<512, 256, 0, stream>>>(q_ws, k2_ws, vt2_ws, out);
}